// Round 1
// baseline (27029.752 us; speedup 1.0000x reference)
//
#include <hip/hip_runtime.h>
#include <hip/hip_bf16.h>
#include <stdint.h>

#define Bdim   128
#define Tdim   1024
#define INdim  256
#define Hdim   256
#define Kdim   512      // IN + H
#define COLSdim 1024    // 4*H
#define NCHUNK 64       // Kdim/8

// W2 layout: [chunk][col][8] bf16 (uint16), chunk = k/8, col in [0,1024)
// offset = (chunk*1024 + col)*8 + (k&7)
__global__ void prep_weights(const float* __restrict__ wx,
                             const float* __restrict__ wh,
                             uint16_t* __restrict__ W2) {
    int id = blockIdx.x * blockDim.x + threadIdx.x;
    if (id >= COLSdim * Kdim) return;
    int r     = id & 7;
    int col   = (id >> 3) & (COLSdim - 1);
    int chunk = id >> 13;
    int k     = chunk * 8 + r;
    float val = (k < INdim) ? wx[(size_t)k * COLSdim + col]
                            : wh[(size_t)(k - INdim) * COLSdim + col];
    __hip_bfloat16 hb = __float2bfloat16(val);
    W2[id] = *reinterpret_cast<uint16_t*>(&hb);
}

__device__ __forceinline__ float blo(uint32_t w) {
    uint32_t u = w << 16;
    union { uint32_t u; float f; } c; c.u = u; return c.f;
}
__device__ __forceinline__ float bhi(uint32_t w) {
    uint32_t u = w & 0xffff0000u;
    union { uint32_t u; float f; } c; c.u = u; return c.f;
}

__device__ __forceinline__ void fma8(uint4 w, float4 va, float4 vb, float& acc) {
    acc = fmaf(blo(w.x), va.x, acc);
    acc = fmaf(bhi(w.x), va.y, acc);
    acc = fmaf(blo(w.y), va.z, acc);
    acc = fmaf(bhi(w.y), va.w, acc);
    acc = fmaf(blo(w.z), vb.x, acc);
    acc = fmaf(bhi(w.z), vb.y, acc);
    acc = fmaf(blo(w.w), vb.z, acc);
    acc = fmaf(bhi(w.w), vb.w, acc);
}

__global__ __launch_bounds__(256, 1) void lstm_main(
    const float* __restrict__ x,      // (B,T,IN)
    const float* __restrict__ h0,     // (B,H)
    const float* __restrict__ c0,     // (B,H)
    const float* __restrict__ bias,   // (1,4H)
    const uint16_t* __restrict__ W2,  // packed bf16 weights
    float* __restrict__ out)          // fullh (B,T,H) ++ h_f (B,H) ++ c_f (B,H)
{
    const int b = blockIdx.x;
    const int t = threadIdx.x;        // hidden unit id, 0..255
    __shared__ __align__(16) float v[Kdim];   // [0,256)=x_t, [256,512)=h

    const float* __restrict__ xb   = x + (size_t)b * Tdim * INdim;
    float* __restrict__       outb = out + (size_t)b * Tdim * Hdim;

    float c = c0[b * Hdim + t];
    v[INdim + t] = h0[b * Hdim + t];

    const float bf_ = bias[t];
    const float bi_ = bias[Hdim + t];
    const float bo_ = bias[2 * Hdim + t];
    const float bg_ = bias[3 * Hdim + t];

    float xreg = xb[t];   // x for step 0
    float hreg = 0.f;

    for (int step = 0; step < Tdim; ++step) {
        v[t] = xreg;
        __syncthreads();   // x_t and h now visible to all

        // prefetch next step's x element (hidden under the dot-product loop)
        int ns = (step + 1 < Tdim) ? step + 1 : step;
        xreg = xb[(size_t)ns * INdim + t];

        float af = 0.f, ai = 0.f, ao = 0.f, ag = 0.f;
        #pragma unroll 8
        for (int ch = 0; ch < NCHUNK; ++ch) {
            const float4 va  = *reinterpret_cast<const float4*>(&v[ch * 8]);
            const float4 vb_ = *reinterpret_cast<const float4*>(&v[ch * 8 + 4]);
            const uint4* wbase =
                reinterpret_cast<const uint4*>(W2 + ((size_t)ch << 13)); // ch*1024*8
            fma8(wbase[t],       va, vb_, af);   // f gate col = t
            fma8(wbase[256 + t], va, vb_, ai);   // i gate col = 256+t
            fma8(wbase[512 + t], va, vb_, ao);   // o gate col = 512+t
            fma8(wbase[768 + t], va, vb_, ag);   // g gate col = 768+t
        }

        float tf = af + bf_, ti = ai + bi_, to = ao + bo_, tg = ag + bg_;
        float fg = 1.f / (1.f + __expf(-tf));
        float ig = 1.f / (1.f + __expf(-ti));
        float og = 1.f / (1.f + __expf(-to));
        float gg = tanhf(tg);
        c    = fmaf(c, fg, gg * ig);
        hreg = tanhf(c) * og;

        __syncthreads();   // everyone done reading v before we overwrite h
        v[INdim + t] = hreg;
        outb[(size_t)step * Hdim + t] = hreg;
        // next iteration's v[t] write + sync makes h visible
    }

    const size_t fullh_sz = (size_t)Bdim * Tdim * Hdim;
    out[fullh_sz + (size_t)b * Hdim + t]                        = hreg;  // h_f
    out[fullh_sz + (size_t)Bdim * Hdim + (size_t)b * Hdim + t]  = c;     // c_f
}

extern "C" void kernel_launch(void* const* d_in, const int* in_sizes, int n_in,
                              void* d_out, int out_size, void* d_ws, size_t ws_size,
                              hipStream_t stream) {
    const float* x    = (const float*)d_in[0];
    const float* h0   = (const float*)d_in[1];
    const float* c0   = (const float*)d_in[2];
    const float* wx   = (const float*)d_in[3];
    const float* wh   = (const float*)d_in[4];
    const float* bias = (const float*)d_in[5];
    uint16_t* W2 = (uint16_t*)d_ws;   // 1 MiB
    float* out = (float*)d_out;

    prep_weights<<<(COLSdim * Kdim + 255) / 256, 256, 0, stream>>>(wx, wh, W2);
    lstm_main<<<Bdim, 256, 0, stream>>>(x, h0, c0, bias, W2, out);
}

// Round 2
// 8207.993 us; speedup vs baseline: 3.2931x; 3.2931x over previous
//
#include <hip/hip_runtime.h>
#include <hip/hip_fp16.h>
#include <stdint.h>

#define Bdim   128
#define Tdim   1024
#define INdim  256
#define Hdim   256
#define Kdim   512      // IN + H
#define COLS   1024     // 4*H
#define NCH    64       // Kdim/8

typedef _Float16 h2_t __attribute__((ext_vector_type(2)));

// W layout: [chunk][col][8] f16, chunk = k/8, col in [0,1024)
// element offset = (chunk*1024 + col)*8 + (k&7)
__global__ void prep_weights(const float* __restrict__ wx,
                             const float* __restrict__ wh,
                             uint16_t* __restrict__ W) {
    int id = blockIdx.x * blockDim.x + threadIdx.x;
    if (id >= COLS * Kdim) return;
    int r   = id & 7;
    int col = (id >> 3) & (COLS - 1);
    int ch  = id >> 13;
    int k   = ch * 8 + r;
    float val = (k < INdim) ? wx[(size_t)k * COLS + col]
                            : wh[(size_t)(k - INdim) * COLS + col];
    __half hv = __float2half(val);
    W[id] = *reinterpret_cast<uint16_t*>(&hv);
}

__device__ __forceinline__ float dot2(uint32_t w, uint32_t v, float acc) {
    return __builtin_amdgcn_fdot2(__builtin_bit_cast(h2_t, w),
                                  __builtin_bit_cast(h2_t, v), acc, false);
}

__device__ __forceinline__ uint16_t f2h(float f) {
    __half h = __float2half(f);
    return *reinterpret_cast<uint16_t*>(&h);
}

// One block = 2 batch elements. 1024 threads: thread t computes gate column t
// for both batches. Roles (wave-aligned, 4 waves each):
//   role 0: state update batch A    role 1: state update batch B
//   role 2: prefetch x_{t+1} A      role 3: prefetch x_{t+1} B
__global__ __launch_bounds__(1024, 1) void lstm_main(
    const float* __restrict__ x,      // (B,T,IN)
    const float* __restrict__ h0,     // (B,H)
    const float* __restrict__ c0,     // (B,H)
    const float* __restrict__ bias,   // (1,4H)
    const uint16_t* __restrict__ W,   // packed f16 weights
    float* __restrict__ out)          // fullh ++ h_f ++ c_f
{
    const int tid = threadIdx.x;
    const int bA = blockIdx.x * 2;
    const int bB = bA + 1;

    __shared__ __align__(16) uint16_t vA[Kdim];   // [0,256)=x_t, [256,512)=h (f16)
    __shared__ __align__(16) uint16_t vB[Kdim];
    __shared__ float gates[2][COLS];

    const float* __restrict__ xA = x + (size_t)bA * Tdim * INdim;
    const float* __restrict__ xB = x + (size_t)bB * Tdim * INdim;
    float* __restrict__ outA = out + (size_t)bA * Tdim * Hdim;
    float* __restrict__ outB = out + (size_t)bB * Tdim * Hdim;

    const int role = tid >> 8;   // wave-uniform
    const int u    = tid & 255;

    float creg = 0.f, hreg = 0.f;
    if (role == 0) {
        creg = c0[bA * Hdim + u];
        vA[INdim + u] = f2h(h0[bA * Hdim + u]);
    } else if (role == 1) {
        creg = c0[bB * Hdim + u];
        vB[INdim + u] = f2h(h0[bB * Hdim + u]);
    } else if (role == 2) {
        vA[u] = f2h(xA[u]);
    } else {
        vB[u] = f2h(xB[u]);
    }
    const float bv = bias[tid];
    __syncthreads();

    for (int step = 0; step < Tdim; ++step) {
        float aA = 0.f, aA2 = 0.f, aB = 0.f, aB2 = 0.f;
        const uint4* __restrict__ wp  = reinterpret_cast<const uint4*>(W) + tid;
        const uint4* __restrict__ vAp = reinterpret_cast<const uint4*>(vA);
        const uint4* __restrict__ vBp = reinterpret_cast<const uint4*>(vB);
        #pragma unroll 4
        for (int ch = 0; ch < NCH; ++ch) {
            uint4 w = wp[(size_t)ch * COLS];
            uint4 a = vAp[ch];
            uint4 b = vBp[ch];
            aA  = dot2(w.x, a.x, aA);  aA  = dot2(w.y, a.y, aA);
            aA2 = dot2(w.z, a.z, aA2); aA2 = dot2(w.w, a.w, aA2);
            aB  = dot2(w.x, b.x, aB);  aB  = dot2(w.y, b.y, aB);
            aB2 = dot2(w.z, b.z, aB2); aB2 = dot2(w.w, b.w, aB2);
        }
        gates[0][tid] = aA + aA2 + bv;
        gates[1][tid] = aB + aB2 + bv;
        __syncthreads();   // gates visible; all reads of vA/vB done

        if (role <= 1) {
            const float* g_ = gates[role];
            float tf = g_[u], ti = g_[Hdim + u], to = g_[2 * Hdim + u], tg = g_[3 * Hdim + u];
            float fg = 1.f / (1.f + __expf(-tf));
            float ig = 1.f / (1.f + __expf(-ti));
            float og = 1.f / (1.f + __expf(-to));
            float gg = tanhf(tg);
            creg = fmaf(creg, fg, gg * ig);
            hreg = tanhf(creg) * og;
            if (role == 0) { vA[INdim + u] = f2h(hreg); outA[(size_t)step * Hdim + u] = hreg; }
            else           { vB[INdim + u] = f2h(hreg); outB[(size_t)step * Hdim + u] = hreg; }
        } else {
            int ns = (step + 1 < Tdim) ? step + 1 : step;
            if (role == 2) vA[u] = f2h(xA[(size_t)ns * INdim + u]);
            else           vB[u] = f2h(xB[(size_t)ns * INdim + u]);
        }
        __syncthreads();   // next step's x/h staged
    }

    const size_t fsz = (size_t)Bdim * Tdim * Hdim;
    if (role == 0) {
        out[fsz + (size_t)bA * Hdim + u] = hreg;
        out[fsz + (size_t)Bdim * Hdim + (size_t)bA * Hdim + u] = creg;
    } else if (role == 1) {
        out[fsz + (size_t)bB * Hdim + u] = hreg;
        out[fsz + (size_t)Bdim * Hdim + (size_t)bB * Hdim + u] = creg;
    }
}

extern "C" void kernel_launch(void* const* d_in, const int* in_sizes, int n_in,
                              void* d_out, int out_size, void* d_ws, size_t ws_size,
                              hipStream_t stream) {
    const float* x    = (const float*)d_in[0];
    const float* h0   = (const float*)d_in[1];
    const float* c0   = (const float*)d_in[2];
    const float* wx   = (const float*)d_in[3];
    const float* wh   = (const float*)d_in[4];
    const float* bias = (const float*)d_in[5];
    uint16_t* W = (uint16_t*)d_ws;   // 1 MiB packed f16 weights
    float* out = (float*)d_out;

    prep_weights<<<(COLS * Kdim + 255) / 256, 256, 0, stream>>>(wx, wh, W);
    lstm_main<<<Bdim / 2, 1024, 0, stream>>>(x, h0, c0, bias, W, out);
}

// Round 3
// 7253.309 us; speedup vs baseline: 3.7265x; 1.1316x over previous
//
#include <hip/hip_runtime.h>
#include <hip/hip_fp16.h>
#include <stdint.h>

#define Bdim 128
#define Tdim 1024
#define INdim 256
#define Hdim 256
#define Kdim 512
#define COLS 1024
#define NSLICE 8
#define NGRP 32
#define GBATCH 4
#define UPB 32       // units per block
#define CPB 128      // cols per block
#define NTHREADS 512
#define RC_STRIDE (Tdim + 1)
#define RC_BYTES (NGRP * RC_STRIDE * 4)   // 131200
#define HBUF_OFF 135168                    // byte offset of hbuf in d_ws

typedef _Float16 h2_t __attribute__((ext_vector_type(2)));

__device__ __forceinline__ float dot2(uint32_t w, uint32_t v, float acc) {
    return __builtin_amdgcn_fdot2(__builtin_bit_cast(h2_t, w),
                                  __builtin_bit_cast(h2_t, v), acc, false);
}
__device__ __forceinline__ uint16_t f2h(float f) {
    __half h = __float2half(f);
    return *reinterpret_cast<uint16_t*>(&h);
}
__device__ __forceinline__ float sigm(float v) {
    return __builtin_amdgcn_rcpf(1.f + __expf(-v));
}
__device__ __forceinline__ float tanhfast(float v) {
    float e = __expf(2.f * v);
    return 1.f - 2.f * __builtin_amdgcn_rcpf(e + 1.f);
}

// hbuf element index: [par][grp][u][b] (f16)
__device__ __forceinline__ size_t hb_idx(int par, int grp, int u, int b) {
    return ((((size_t)par * NGRP + grp) * Hdim + u) * GBATCH + b);
}

__global__ __launch_bounds__(NTHREADS, 1) void lstm_main(
    const float* __restrict__ x, const float* __restrict__ h0,
    const float* __restrict__ c0, const float* __restrict__ wx,
    const float* __restrict__ wh, const float* __restrict__ bias,
    float* __restrict__ out, uint32_t* rc, uint16_t* hbuf)
{
    const int tid   = threadIdx.x;
    const int bid   = blockIdx.x;
    const int slice = bid >> 5;          // 0..7
    const int grp   = bid & 31;          // 0..31
    const int lane  = tid & 63;
    const int wave  = tid >> 6;
    const int c_local  = (wave << 4) | (lane & 15);  // 0..127
    const int b        = (lane >> 4) & 3;            // 0..3 (in-wave -> W broadcast)
    const int u_local  = c_local >> 2;
    const int g        = c_local & 3;                // 0=f 1=i 2=o 3=g
    const int u_global = slice * UPB + u_local;
    const int col      = g * Hdim + u_global;
    const int bg       = grp * GBATCH + b;

    // 128 KiB swizzled weight slice + double-buffered activation vector
    __shared__ __align__(16) uint16_t Wlds[CPB * Kdim];      // 131072 B
    __shared__ __align__(16) uint16_t vbuf[2][GBATCH][Kdim]; //   8192 B

    // ---- prologue: load W slice (f32 -> f16, XOR-swizzled 16B slots) ----
    for (int idx = tid; idx < CPB * Kdim; idx += NTHREADS) {
        int c  = idx & (CPB - 1);        // fixed per thread
        int k  = idx >> 7;
        int ug = slice * UPB + (c >> 2);
        int cg = (c & 3) * Hdim + ug;
        float w = (k < INdim) ? wx[(size_t)k * COLS + cg]
                              : wh[(size_t)(k - INdim) * COLS + cg];
        int e = c * 512 + ((((k >> 3) ^ (c & 7)) << 3) | (k & 7));
        Wlds[e] = f2h(w);
    }
    // stage x_0 into vbuf[0] x-half
    {
        int bb = tid >> 7;
        int kx = (tid & 127) << 1;
        const float2 xv = *reinterpret_cast<const float2*>(
            &x[((size_t)(grp * GBATCH + bb) * Tdim + 0) * INdim + kx]);
        vbuf[0][bb][kx]     = f2h(xv.x);
        vbuf[0][bb][kx + 1] = f2h(xv.y);
    }
    // init hbuf[0] (own unit slice, all 4 batches via g==0 lanes)
    if (g == 0) {
        float hv = h0[(size_t)bg * Hdim + u_global];
        __hip_atomic_store(&hbuf[hb_idx(0, grp, u_global, b)], f2h(hv),
                           __ATOMIC_RELAXED, __HIP_MEMORY_SCOPE_AGENT);
    }
    float c_reg = c0[(size_t)bg * Hdim + u_global];
    const float bv = bias[col];
    __syncthreads();
    if (tid == 0)
        __hip_atomic_fetch_add(&rc[grp * RC_STRIDE + 0], 1u,
                               __ATOMIC_RELEASE, __HIP_MEMORY_SCOPE_AGENT);

    const uint32_t xc = (uint32_t)(c_local & 7);
    const uint16_t* wrow = &Wlds[c_local * 512];
    float hreg = 0.f;

    for (int t = 0; t < Tdim; ++t) {
        const int par = t & 1;
        const int pn  = (t + 1) & 1;

        // issue x_{t+1} prefetch (global, hidden under x-dot + spin)
        float2 xv;
        const int bb = tid >> 7;
        const int kx = (tid & 127) << 1;
        {
            int tn = (t + 1 < Tdim) ? t + 1 : t;
            xv = *reinterpret_cast<const float2*>(
                &x[((size_t)(grp * GBATCH + bb) * Tdim + tn) * INdim + kx]);
        }

        // x-part dot (k 0..255) — doesn't need h, runs before the spin
        const uint16_t* vrow = &vbuf[par][b][0];
        float a0 = 0.f, a1 = 0.f;
        #pragma unroll 8
        for (int j = 0; j < 32; j += 2) {
            uint4 w0 = *reinterpret_cast<const uint4*>(&wrow[(j ^ xc) << 3]);
            uint4 w1 = *reinterpret_cast<const uint4*>(&wrow[((j + 1) ^ xc) << 3]);
            uint4 v0 = *reinterpret_cast<const uint4*>(&vrow[j * 8]);
            uint4 v1 = *reinterpret_cast<const uint4*>(&vrow[j * 8 + 8]);
            a0 = dot2(w0.x, v0.x, a0); a0 = dot2(w0.y, v0.y, a0);
            a0 = dot2(w0.z, v0.z, a0); a0 = dot2(w0.w, v0.w, a0);
            a1 = dot2(w1.x, v1.x, a1); a1 = dot2(w1.y, v1.y, a1);
            a1 = dot2(w1.z, v1.z, a1); a1 = dot2(w1.w, v1.w, a1);
        }

        // wait for h_{t-1} from all 8 slices of this group
        if (tid == 0) {
            while (__hip_atomic_load(&rc[grp * RC_STRIDE + t],
                                     __ATOMIC_ACQUIRE, __HIP_MEMORY_SCOPE_AGENT) < NSLICE) {}
        }
        __syncthreads();

        // stage h into vbuf[par] h-half (coherent-point loads)
        if (tid < Hdim) {
            unsigned long long hv8 = __hip_atomic_load(
                reinterpret_cast<unsigned long long*>(&hbuf[hb_idx(par, grp, tid, 0)]),
                __ATOMIC_RELAXED, __HIP_MEMORY_SCOPE_AGENT);
            uint16_t* p = reinterpret_cast<uint16_t*>(&hv8);
            vbuf[par][0][INdim + tid] = p[0];
            vbuf[par][1][INdim + tid] = p[1];
            vbuf[par][2][INdim + tid] = p[2];
            vbuf[par][3][INdim + tid] = p[3];
        }
        __syncthreads();

        // h-part dot (k 256..511)
        #pragma unroll 8
        for (int j = 32; j < 64; j += 2) {
            uint4 w0 = *reinterpret_cast<const uint4*>(&wrow[(j ^ xc) << 3]);
            uint4 w1 = *reinterpret_cast<const uint4*>(&wrow[((j + 1) ^ xc) << 3]);
            uint4 v0 = *reinterpret_cast<const uint4*>(&vrow[j * 8]);
            uint4 v1 = *reinterpret_cast<const uint4*>(&vrow[j * 8 + 8]);
            a0 = dot2(w0.x, v0.x, a0); a0 = dot2(w0.y, v0.y, a0);
            a0 = dot2(w0.z, v0.z, a0); a0 = dot2(w0.w, v0.w, a0);
            a1 = dot2(w1.x, v1.x, a1); a1 = dot2(w1.y, v1.y, a1);
            a1 = dot2(w1.z, v1.z, a1); a1 = dot2(w1.w, v1.w, a1);
        }
        float tval = a0 + a1 + bv;

        // one transcendental per lane, then exchange f/i/o/g in 4-lane bundle
        float act = (g == 3) ? tanhfast(tval) : sigm(tval);
        float x1  = __shfl_xor(act, 1);
        float e0  = (g & 1) ? x1 : act;
        float o1  = (g & 1) ? act : x1;
        float e0s = __shfl_xor(e0, 2);
        float o1s = __shfl_xor(o1, 2);
        float f_ = (g < 2) ? e0  : e0s;
        float i_ = (g < 2) ? o1  : o1s;
        float o_ = (g < 2) ? e0s : e0;
        float g_ = (g < 2) ? o1s : o1;
        c_reg = fmaf(c_reg, f_, g_ * i_);
        hreg  = tanhfast(c_reg) * o_;

        // publish h_t (coherent-point store) + fullh output
        if (g == 0) {
            __hip_atomic_store(&hbuf[hb_idx(pn, grp, u_global, b)], f2h(hreg),
                               __ATOMIC_RELAXED, __HIP_MEMORY_SCOPE_AGENT);
            out[((size_t)bg * Tdim + t) * Hdim + u_global] = hreg;
        }
        // stage x_{t+1} into vbuf[pn] x-half
        vbuf[pn][bb][kx]     = f2h(xv.x);
        vbuf[pn][bb][kx + 1] = f2h(xv.y);

        __syncthreads();   // drains all waves' stores (vmcnt 0) before flag
        if (tid == 0)
            __hip_atomic_fetch_add(&rc[grp * RC_STRIDE + t + 1], 1u,
                                   __ATOMIC_RELEASE, __HIP_MEMORY_SCOPE_AGENT);
    }

    if (g == 0) {
        const size_t fsz = (size_t)Bdim * Tdim * Hdim;
        out[fsz + (size_t)bg * Hdim + u_global] = hreg;                              // h_f
        out[fsz + (size_t)Bdim * Hdim + (size_t)bg * Hdim + u_global] = c_reg;       // c_f
    }
}

extern "C" void kernel_launch(void* const* d_in, const int* in_sizes, int n_in,
                              void* d_out, int out_size, void* d_ws, size_t ws_size,
                              hipStream_t stream) {
    const float* x    = (const float*)d_in[0];
    const float* h0   = (const float*)d_in[1];
    const float* c0   = (const float*)d_in[2];
    const float* wx   = (const float*)d_in[3];
    const float* wh   = (const float*)d_in[4];
    const float* bias = (const float*)d_in[5];
    float* out = (float*)d_out;
    uint32_t* rc   = (uint32_t*)d_ws;
    uint16_t* hbuf = (uint16_t*)((char*)d_ws + HBUF_OFF);

    hipMemsetAsync(rc, 0, RC_BYTES, stream);

    void* args[] = {(void*)&x, (void*)&h0, (void*)&c0, (void*)&wx, (void*)&wh,
                    (void*)&bias, (void*)&out, (void*)&rc, (void*)&hbuf};
    hipLaunchCooperativeKernel((const void*)lstm_main, dim3(NSLICE * NGRP),
                               dim3(NTHREADS), args, 0, stream);
}

// Round 4
// 4888.599 us; speedup vs baseline: 5.5291x; 1.4837x over previous
//
#include <hip/hip_runtime.h>
#include <hip/hip_fp16.h>
#include <stdint.h>

#define Tdim 1024
#define INdim 256
#define Hdim 256
#define COLS 1024
#define NSLICE 8
#define NGRP 8
#define GB 16          // batches per group (MFMA M)
#define UPB 32         // units per slice
#define CPB 128        // cols per block
#define NTHREADS 512
#define FLAG_STRIDE ((Tdim + 1) * NSLICE)
#define FLAG_BYTES (NGRP * FLAG_STRIDE * 4)   // 262,400
#define HBUF_OFF 266240                        // hbuf: [2][NGRP][GB][Hdim] f16 = 131,072 B

typedef _Float16 half8 __attribute__((ext_vector_type(8)));
typedef float f32x4 __attribute__((ext_vector_type(4)));

__device__ __forceinline__ uint16_t f2h(float f) {
    __half h = __float2half(f);
    return *reinterpret_cast<uint16_t*>(&h);
}
__device__ __forceinline__ float sigm(float v) {
    return __builtin_amdgcn_rcpf(1.f + __expf(-v));
}
__device__ __forceinline__ float tanhfast(float v) {
    float e = __expf(2.f * v);
    return 1.f - 2.f * __builtin_amdgcn_rcpf(e + 1.f);
}
__device__ __forceinline__ size_t hb_idx(int par, int grp, int m, int u) {
    return ((((size_t)par * NGRP + grp) * GB + m) << 8) | (size_t)u;
}

// MFMA 16x16x32 f16 lane roles (gfx950):
//   A: lane l -> row = l&15, k = (l>>4)*8 + e   (e=0..7)
//   B: lane l -> col = l&15, k = (l>>4)*8 + e
//   C/D: lane l, reg r -> row = (l>>4)*4 + r, col = l&15   [m89-verified]
__global__ __launch_bounds__(NTHREADS, 1) void lstm_main(
    const float* __restrict__ x, const float* __restrict__ h0,
    const float* __restrict__ c0, const float* __restrict__ wx,
    const float* __restrict__ wh, const float* __restrict__ bias,
    float* __restrict__ out, uint32_t* flags, uint16_t* hbuf)
{
    const int tid   = threadIdx.x;
    const int grp   = blockIdx.x & 7;     // all slices of a grp land on one XCD (perf only)
    const int slice = blockIdx.x >> 3;
    const int lane  = tid & 63;
    const int wave  = tid >> 6;
    const int cw    = lane & 15;
    const int lhi   = lane >> 4;          // 0..3
    const int cl    = wave * 16 + cw;     // block-local col: (u_local<<2)|g
    const int g     = cl & 3;
    const int u     = slice * UPB + (cl >> 2);
    const int gcol  = g * Hdim + u;

    __shared__ __align__(16) uint16_t Wl[CPB * 512];     // 128 KB, [cl][k] xor-swizzled
    __shared__ __align__(16) uint16_t X[2][32][GB][8];   // 16 KB  (k-oct, m)
    __shared__ __align__(16) uint16_t Hs[32][GB][8];     // 8 KB

    // ---------- prologue ----------
    for (int idx = tid; idx < CPB * 512; idx += NTHREADS) {
        int k  = idx >> 7;
        int ci = idx & 127;
        int ul = ci & 31, gg = ci >> 5;
        int cg = gg * Hdim + slice * UPB + ul;          // global col (coalesced over ul)
        int c  = (ul << 2) | gg;                        // block-local col
        float w = (k < INdim) ? wx[(size_t)k * COLS + cg]
                              : wh[(size_t)(k - INdim) * COLS + cg];
        int e = c * 512 + ((((k >> 3) ^ (c & 7)) << 3) | (k & 7));
        Wl[e] = f2h(w);
    }
    {   // stage x_0
        int m = tid >> 5, ko = tid & 31;
        const float4* xs = reinterpret_cast<const float4*>(
            &x[((size_t)(grp * GB + m) * Tdim + 0) * INdim + ko * 8]);
        float4 a = xs[0], b = xs[1];
        uint16_t* xd = &X[0][ko][m][0];
        xd[0]=f2h(a.x); xd[1]=f2h(a.y); xd[2]=f2h(a.z); xd[3]=f2h(a.w);
        xd[4]=f2h(b.x); xd[5]=f2h(b.y); xd[6]=f2h(b.z); xd[7]=f2h(b.w);
    }
    if (tid < 64) {  // h0 -> hbuf[0] (own slice's units)
        int m = tid >> 2, uo = tid & 3;
        int u0 = slice * UPB + uo * 8;
        const float4* hs = reinterpret_cast<const float4*>(
            &h0[(size_t)(grp * GB + m) * Hdim + u0]);
        float4 a = hs[0], b = hs[1];
        unsigned long long p0, p1;
        uint16_t* q0 = reinterpret_cast<uint16_t*>(&p0);
        uint16_t* q1 = reinterpret_cast<uint16_t*>(&p1);
        q0[0]=f2h(a.x); q0[1]=f2h(a.y); q0[2]=f2h(a.z); q0[3]=f2h(a.w);
        q1[0]=f2h(b.x); q1[1]=f2h(b.y); q1[2]=f2h(b.z); q1[3]=f2h(b.w);
        unsigned long long* hp =
            reinterpret_cast<unsigned long long*>(&hbuf[hb_idx(0, grp, m, u0)]);
        __hip_atomic_store(&hp[0], p0, __ATOMIC_RELAXED, __HIP_MEMORY_SCOPE_AGENT);
        __hip_atomic_store(&hp[1], p1, __ATOMIC_RELAXED, __HIP_MEMORY_SCOPE_AGENT);
    }
    float c_reg[4];
    #pragma unroll
    for (int r = 0; r < 4; ++r)
        c_reg[r] = c0[(size_t)(grp * GB + lhi * 4 + r) * Hdim + u];
    const float bv = bias[gcol];
    __syncthreads();
    uint32_t* fl = flags + grp * FLAG_STRIDE;
    if (tid == 0)
        __hip_atomic_store(&fl[slice], 1u, __ATOMIC_RELEASE, __HIP_MEMORY_SCOPE_AGENT);

    const uint32_t swz = (uint32_t)(cl & 7);
    const uint16_t* wrow = &Wl[cl * 512];
    float hv[4] = {0.f, 0.f, 0.f, 0.f};

    // ---------- time loop ----------
    for (int t = 0; t < Tdim; ++t) {
        const int par = t & 1, pn = par ^ 1;

        // prefetch x_{t+1} into regs
        int tn = (t + 1 < Tdim) ? t + 1 : t;
        const int m_s = tid >> 5, ko_s = tid & 31;
        const float4* xs = reinterpret_cast<const float4*>(
            &x[((size_t)(grp * GB + m_s) * Tdim + tn) * INdim + ko_s * 8]);
        float4 xp0 = xs[0], xp1 = xs[1];

        // x-part GEMM (k 0..255) — independent of h(t)
        f32x4 acc0 = {0.f, 0.f, 0.f, 0.f}, acc1 = {0.f, 0.f, 0.f, 0.f};
        #pragma unroll
        for (int s = 0; s < 8; s += 2) {
            int ko0 = s * 4 + lhi, ko1 = ko0 + 4;
            half8 a0 = *reinterpret_cast<const half8*>(&X[par][ko0][cw][0]);
            half8 b0 = *reinterpret_cast<const half8*>(&wrow[(ko0 ^ swz) << 3]);
            acc0 = __builtin_amdgcn_mfma_f32_16x16x32_f16(a0, b0, acc0, 0, 0, 0);
            half8 a1 = *reinterpret_cast<const half8*>(&X[par][ko1][cw][0]);
            half8 b1 = *reinterpret_cast<const half8*>(&wrow[(ko1 ^ swz) << 3]);
            acc1 = __builtin_amdgcn_mfma_f32_16x16x32_f16(a1, b1, acc1, 0, 0, 0);
        }

        // wait for h(t) from all 8 slices
        if (tid < 8) {
            while (__hip_atomic_load(&fl[t * NSLICE + tid], __ATOMIC_ACQUIRE,
                                     __HIP_MEMORY_SCOPE_AGENT) == 0) {}
        }
        __syncthreads();

        // stage h -> Hs
        {
            const unsigned long long* hp = reinterpret_cast<const unsigned long long*>(
                &hbuf[hb_idx(par, grp, m_s, ko_s * 8)]);
            unsigned long long h0v = __hip_atomic_load(&hp[0], __ATOMIC_RELAXED,
                                                       __HIP_MEMORY_SCOPE_AGENT);
            unsigned long long h1v = __hip_atomic_load(&hp[1], __ATOMIC_RELAXED,
                                                       __HIP_MEMORY_SCOPE_AGENT);
            *reinterpret_cast<unsigned long long*>(&Hs[ko_s][m_s][0]) = h0v;
            *reinterpret_cast<unsigned long long*>(&Hs[ko_s][m_s][4]) = h1v;
        }
        __syncthreads();

        // h-part GEMM (k 256..511)
        #pragma unroll
        for (int s = 0; s < 8; s += 2) {
            int ko0 = s * 4 + lhi, ko1 = ko0 + 4;
            half8 a0 = *reinterpret_cast<const half8*>(&Hs[ko0][cw][0]);
            half8 b0 = *reinterpret_cast<const half8*>(&wrow[((32 + ko0) ^ swz) << 3]);
            acc0 = __builtin_amdgcn_mfma_f32_16x16x32_f16(a0, b0, acc0, 0, 0, 0);
            half8 a1 = *reinterpret_cast<const half8*>(&Hs[ko1][cw][0]);
            half8 b1 = *reinterpret_cast<const half8*>(&wrow[((32 + ko1) ^ swz) << 3]);
            acc1 = __builtin_amdgcn_mfma_f32_16x16x32_f16(a1, b1, acc1, 0, 0, 0);
        }

        // gates + state update (4 rows per lane)
        #pragma unroll
        for (int r = 0; r < 4; ++r) {
            float tval = acc0[r] + acc1[r] + bv;
            float act = (g == 3) ? tanhfast(tval) : sigm(tval);
            float x1  = __shfl_xor(act, 1);
            float e0  = (g & 1) ? x1 : act;
            float o1  = (g & 1) ? act : x1;
            float e0s = __shfl_xor(e0, 2);
            float o1s = __shfl_xor(o1, 2);
            float f_ = (g < 2) ? e0  : e0s;
            float i_ = (g < 2) ? o1  : o1s;
            float o_ = (g < 2) ? e0s : e0;
            float g_ = (g < 2) ? o1s : o1;
            c_reg[r] = fmaf(c_reg[r], f_, g_ * i_);
            hv[r] = tanhfast(c_reg[r]) * o_;
        }

        // publish h(t+1-input) + fullh
        if (g == 0) {
            #pragma unroll
            for (int r = 0; r < 4; ++r) {
                int m = lhi * 4 + r;
                __hip_atomic_store(&hbuf[hb_idx(pn, grp, m, u)], f2h(hv[r]),
                                   __ATOMIC_RELAXED, __HIP_MEMORY_SCOPE_AGENT);
                out[((size_t)(grp * GB + m) * Tdim + t) * Hdim + u] = hv[r];
            }
        }
        // stage x_{t+1}
        {
            uint16_t* xd = &X[pn][ko_s][m_s][0];
            xd[0]=f2h(xp0.x); xd[1]=f2h(xp0.y); xd[2]=f2h(xp0.z); xd[3]=f2h(xp0.w);
            xd[4]=f2h(xp1.x); xd[5]=f2h(xp1.y); xd[6]=f2h(xp1.z); xd[7]=f2h(xp1.w);
        }
        __syncthreads();          // stores drained (vmcnt 0) before flag
        if (tid == 0)
            __hip_atomic_store(&fl[(t + 1) * NSLICE + slice], 1u,
                               __ATOMIC_RELEASE, __HIP_MEMORY_SCOPE_AGENT);
    }

    // final h_f, c_f
    if (g == 0) {
        const size_t fsz = (size_t)(NGRP * GB) * Tdim * Hdim;
        #pragma unroll
        for (int r = 0; r < 4; ++r) {
            int m = lhi * 4 + r;
            out[fsz + (size_t)(grp * GB + m) * Hdim + u] = hv[r];
            out[fsz + (size_t)(NGRP * GB) * Hdim + (size_t)(grp * GB + m) * Hdim + u] = c_reg[r];
        }
    }
}

extern "C" void kernel_launch(void* const* d_in, const int* in_sizes, int n_in,
                              void* d_out, int out_size, void* d_ws, size_t ws_size,
                              hipStream_t stream) {
    const float* x    = (const float*)d_in[0];
    const float* h0   = (const float*)d_in[1];
    const float* c0   = (const float*)d_in[2];
    const float* wx   = (const float*)d_in[3];
    const float* wh   = (const float*)d_in[4];
    const float* bias = (const float*)d_in[5];
    float* out = (float*)d_out;
    uint32_t* flags = (uint32_t*)d_ws;
    uint16_t* hbuf  = (uint16_t*)((char*)d_ws + HBUF_OFF);

    hipMemsetAsync(flags, 0, FLAG_BYTES, stream);

    void* args[] = {(void*)&x, (void*)&h0, (void*)&c0, (void*)&wx, (void*)&wh,
                    (void*)&bias, (void*)&out, (void*)&flags, (void*)&hbuf};
    hipLaunchCooperativeKernel((const void*)lstm_main, dim3(NSLICE * NGRP),
                               dim3(NTHREADS), args, 0, stream);
}

// Round 5
// 2600.858 us; speedup vs baseline: 10.3926x; 1.8796x over previous
//
#include <hip/hip_runtime.h>
#include <hip/hip_fp16.h>
#include <stdint.h>

#define Tdim 1024
#define INdim 256
#define Hdim 256
#define COLS 1024
#define NSLICE 8
#define NGRP 8
#define GB 16          // batches per group (MFMA M)
#define UPB 32         // units per slice
#define CPB 128        // cols per block
#define NTHREADS 512
#define FLAG_STRIDE ((Tdim + 1) * NSLICE)
#define FLAG_BYTES (NGRP * FLAG_STRIDE * 4)   // 262,400
#define HBUF_OFF 266240                        // hbuf: [2][NGRP][GB][Hdim] f16 = 131,072 B

typedef _Float16 half8 __attribute__((ext_vector_type(8)));
typedef float f32x4 __attribute__((ext_vector_type(4)));

__device__ __forceinline__ uint16_t f2h(float f) {
    __half h = __float2half(f);
    return *reinterpret_cast<uint16_t*>(&h);
}
__device__ __forceinline__ float sigm(float v) {
    return __builtin_amdgcn_rcpf(1.f + __expf(-v));
}
__device__ __forceinline__ float tanhfast(float v) {
    float e = __expf(2.f * v);
    return 1.f - 2.f * __builtin_amdgcn_rcpf(e + 1.f);
}
__device__ __forceinline__ size_t hb_idx(int par, int grp, int m, int u) {
    return ((((size_t)par * NGRP + grp) * GB + m) << 8) | (size_t)u;
}

// MFMA 16x16x32 f16 lane roles (verified passing r4):
//   A: lane l -> row(m) = l&15, k = (l>>4)*8 + e
//   B: lane l -> col    = l&15 (via per-lane wrow), k = (l>>4)*8 + e
//   C/D: lane l, reg r -> row(m) = (l>>4)*4 + r, col = l&15
__global__ __launch_bounds__(NTHREADS, 1) void lstm_main(
    const float* __restrict__ x, const float* __restrict__ h0,
    const float* __restrict__ c0, const float* __restrict__ wx,
    const float* __restrict__ wh, const float* __restrict__ bias,
    float* __restrict__ out, uint32_t* flags, uint16_t* hbuf)
{
    const int tid   = threadIdx.x;
    const int grp   = blockIdx.x & 7;     // slices of a grp share an XCD (perf heuristic only)
    const int slice = blockIdx.x >> 3;
    const int lane  = tid & 63;
    const int wave  = tid >> 6;
    const int cw    = lane & 15;
    const int lhi   = lane >> 4;          // 0..3
    const int cl    = wave * 16 + cw;     // block-local col: (u_local<<2)|g
    const int g     = cl & 3;
    const int ul    = cl >> 2;            // 0..31
    const int u     = slice * UPB + ul;
    const int gcol  = g * Hdim + u;

    __shared__ __align__(16) uint16_t Wl[CPB * 512];     // 128 KB, [cl][k] xor-swizzled
    __shared__ __align__(16) uint16_t X[2][32][GB][8];   // 16 KB  (k-oct, m)
    __shared__ __align__(16) uint16_t Hs[32][GB][8];     // 8 KB
    __shared__ __align__(16) uint16_t Hp16[GB][UPB];     // 1 KB   publish staging (f16)
    __shared__ __align__(16) float    Hpf[GB][UPB];      // 2 KB   fullh staging (f32)

    // ---------- prologue ----------
    for (int idx = tid; idx < CPB * 512; idx += NTHREADS) {
        int k  = idx >> 7;
        int ci = idx & 127;
        int uu = ci & 31, gg = ci >> 5;
        int cg = gg * Hdim + slice * UPB + uu;          // global col (coalesced over uu)
        int c  = (uu << 2) | gg;                        // block-local col
        float w = (k < INdim) ? wx[(size_t)k * COLS + cg]
                              : wh[(size_t)(k - INdim) * COLS + cg];
        int e = c * 512 + ((((k >> 3) ^ (c & 7)) << 3) | (k & 7));
        Wl[e] = f2h(w);
    }
    const int m_s  = tid >> 5;            // staging row (batch)
    const int ko_s = tid & 31;            // staging k-oct
    {   // stage x_0 directly
        const float4* xs = reinterpret_cast<const float4*>(
            &x[((size_t)(grp * GB + m_s) * Tdim + 0) * INdim + ko_s * 8]);
        float4 a = xs[0], b = xs[1];
        uint16_t* xd = &X[0][ko_s][m_s][0];
        xd[0]=f2h(a.x); xd[1]=f2h(a.y); xd[2]=f2h(a.z); xd[3]=f2h(a.w);
        xd[4]=f2h(b.x); xd[5]=f2h(b.y); xd[6]=f2h(b.z); xd[7]=f2h(b.w);
    }
    // prefetch x_1 into regs
    float4 xp0, xp1;
    {
        const float4* xs = reinterpret_cast<const float4*>(
            &x[((size_t)(grp * GB + m_s) * Tdim + 1) * INdim + ko_s * 8]);
        xp0 = xs[0]; xp1 = xs[1];
    }
    if (tid < 64) {  // h0 -> hbuf[0] (own slice's units), relaxed 8B stores
        int m = tid >> 2, uo = tid & 3;
        int u0 = slice * UPB + uo * 8;
        const float4* hs = reinterpret_cast<const float4*>(
            &h0[(size_t)(grp * GB + m) * Hdim + u0]);
        float4 a = hs[0], b = hs[1];
        unsigned long long p0, p1;
        uint16_t* q0 = reinterpret_cast<uint16_t*>(&p0);
        uint16_t* q1 = reinterpret_cast<uint16_t*>(&p1);
        q0[0]=f2h(a.x); q0[1]=f2h(a.y); q0[2]=f2h(a.z); q0[3]=f2h(a.w);
        q1[0]=f2h(b.x); q1[1]=f2h(b.y); q1[2]=f2h(b.z); q1[3]=f2h(b.w);
        unsigned long long* hp =
            reinterpret_cast<unsigned long long*>(&hbuf[hb_idx(0, grp, m, u0)]);
        __hip_atomic_store(&hp[0], p0, __ATOMIC_RELAXED, __HIP_MEMORY_SCOPE_AGENT);
        __hip_atomic_store(&hp[1], p1, __ATOMIC_RELAXED, __HIP_MEMORY_SCOPE_AGENT);
    }
    float c_reg[4];
    #pragma unroll
    for (int r = 0; r < 4; ++r)
        c_reg[r] = c0[(size_t)(grp * GB + lhi * 4 + r) * Hdim + u];
    const float bv = bias[gcol];
    __syncthreads();   // implicit vmcnt(0): hbuf init acked at coherence point
    uint32_t* fl = flags + grp * FLAG_STRIDE;
    if (tid == 0)
        __hip_atomic_store(&fl[slice], 1u, __ATOMIC_RELAXED, __HIP_MEMORY_SCOPE_AGENT);

    const uint32_t swz = (uint32_t)(cl & 7);
    const uint16_t* wrow = &Wl[cl * 512];
    float hv[4] = {0.f, 0.f, 0.f, 0.f};

    // ---------- time loop ----------
    for (int t = 0; t < Tdim; ++t) {
        const int par = t & 1, pn = par ^ 1;

        // stage x_{t+1} from regs (loaded last iteration; no stall)
        {
            uint16_t* xd = &X[pn][ko_s][m_s][0];
            xd[0]=f2h(xp0.x); xd[1]=f2h(xp0.y); xd[2]=f2h(xp0.z); xd[3]=f2h(xp0.w);
            xd[4]=f2h(xp1.x); xd[5]=f2h(xp1.y); xd[6]=f2h(xp1.z); xd[7]=f2h(xp1.w);
        }
        // issue prefetch of x_{t+2}
        {
            int tn = (t + 2 < Tdim) ? t + 2 : Tdim - 1;
            const float4* xs = reinterpret_cast<const float4*>(
                &x[((size_t)(grp * GB + m_s) * Tdim + tn) * INdim + ko_s * 8]);
            xp0 = xs[0]; xp1 = xs[1];
        }

        // x-part GEMM (k 0..255) — independent of h(t)
        f32x4 acc0 = {0.f, 0.f, 0.f, 0.f}, acc1 = {0.f, 0.f, 0.f, 0.f};
        #pragma unroll
        for (int s = 0; s < 8; s += 2) {
            int ko0 = s * 4 + lhi, ko1 = ko0 + 4;
            half8 a0 = *reinterpret_cast<const half8*>(&X[par][ko0][cw][0]);
            half8 b0 = *reinterpret_cast<const half8*>(&wrow[(ko0 ^ swz) << 3]);
            acc0 = __builtin_amdgcn_mfma_f32_16x16x32_f16(a0, b0, acc0, 0, 0, 0);
            half8 a1 = *reinterpret_cast<const half8*>(&X[par][ko1][cw][0]);
            half8 b1 = *reinterpret_cast<const half8*>(&wrow[(ko1 ^ swz) << 3]);
            acc1 = __builtin_amdgcn_mfma_f32_16x16x32_f16(a1, b1, acc1, 0, 0, 0);
        }

        // wait for h(t) from all 8 slices — relaxed polls, no cache maintenance
        if (tid < NSLICE) {
            while (__hip_atomic_load(&fl[t * NSLICE + tid], __ATOMIC_RELAXED,
                                     __HIP_MEMORY_SCOPE_AGENT) == 0) {}
        }
        __syncthreads();

        // stage h -> Hs (relaxed coherence-point loads, coalesced 16B/thread)
        {
            const unsigned long long* hp = reinterpret_cast<const unsigned long long*>(
                &hbuf[hb_idx(par, grp, m_s, ko_s * 8)]);
            unsigned long long h0v = __hip_atomic_load(&hp[0], __ATOMIC_RELAXED,
                                                       __HIP_MEMORY_SCOPE_AGENT);
            unsigned long long h1v = __hip_atomic_load(&hp[1], __ATOMIC_RELAXED,
                                                       __HIP_MEMORY_SCOPE_AGENT);
            *reinterpret_cast<unsigned long long*>(&Hs[ko_s][m_s][0]) = h0v;
            *reinterpret_cast<unsigned long long*>(&Hs[ko_s][m_s][4]) = h1v;
        }
        __syncthreads();

        // h-part GEMM (k 256..511)
        #pragma unroll
        for (int s = 0; s < 8; s += 2) {
            int ko0 = s * 4 + lhi, ko1 = ko0 + 4;
            half8 a0 = *reinterpret_cast<const half8*>(&Hs[ko0][cw][0]);
            half8 b0 = *reinterpret_cast<const half8*>(&wrow[((32 + ko0) ^ swz) << 3]);
            acc0 = __builtin_amdgcn_mfma_f32_16x16x32_f16(a0, b0, acc0, 0, 0, 0);
            half8 a1 = *reinterpret_cast<const half8*>(&Hs[ko1][cw][0]);
            half8 b1 = *reinterpret_cast<const half8*>(&wrow[((32 + ko1) ^ swz) << 3]);
            acc1 = __builtin_amdgcn_mfma_f32_16x16x32_f16(a1, b1, acc1, 0, 0, 0);
        }

        // gates + state update (4 rows per lane)
        #pragma unroll
        for (int r = 0; r < 4; ++r) {
            float tval = acc0[r] + acc1[r] + bv;
            float act = (g == 3) ? tanhfast(tval) : sigm(tval);
            float x1  = __shfl_xor(act, 1);
            float e0  = (g & 1) ? x1 : act;
            float o1  = (g & 1) ? act : x1;
            float e0s = __shfl_xor(e0, 2);
            float o1s = __shfl_xor(o1, 2);
            float f_ = (g < 2) ? e0  : e0s;
            float i_ = (g < 2) ? o1  : o1s;
            float o_ = (g < 2) ? e0s : e0;
            float g_ = (g < 2) ? o1s : o1;
            c_reg[r] = fmaf(c_reg[r], f_, g_ * i_);
            hv[r] = tanhfast(c_reg[r]) * o_;
        }

        // drop h into LDS staging tiles
        if (g == 0) {
            #pragma unroll
            for (int r = 0; r < 4; ++r) {
                int m = lhi * 4 + r;
                Hp16[m][ul] = f2h(hv[r]);
                Hpf[m][ul]  = hv[r];
            }
        }
        __syncthreads();

        // publish: 128 coalesced 8B relaxed stores (16 full cache lines)
        if (tid < 128) {
            int m = tid >> 3, q = tid & 7;
            unsigned long long v =
                *reinterpret_cast<const unsigned long long*>(&Hp16[m][q * 4]);
            __hip_atomic_store(reinterpret_cast<unsigned long long*>(
                                   &hbuf[hb_idx(pn, grp, m, slice * UPB + q * 4)]),
                               v, __ATOMIC_RELAXED, __HIP_MEMORY_SCOPE_AGENT);
        }
        __syncthreads();   // implicit vmcnt(0): publish acked before flag
        if (tid == 0)
            __hip_atomic_store(&fl[(t + 1) * NSLICE + slice], 1u,
                               __ATOMIC_RELAXED, __HIP_MEMORY_SCOPE_AGENT);

        // fullh stores — after the flag, off the critical path (waves 2-3)
        if (tid >= 128 && tid < 256) {
            int j = tid - 128;
            int m = j >> 3, q = j & 7;
            float4 v = *reinterpret_cast<const float4*>(&Hpf[m][q * 4]);
            *reinterpret_cast<float4*>(
                &out[((size_t)(grp * GB + m) * Tdim + t) * Hdim + slice * UPB + q * 4]) = v;
        }
    }

    // final h_f, c_f
    if (g == 0) {
        const size_t fsz = (size_t)(NGRP * GB) * Tdim * Hdim;
        #pragma unroll
        for (int r = 0; r < 4; ++r) {
            int m = lhi * 4 + r;
            out[fsz + (size_t)(grp * GB + m) * Hdim + u] = hv[r];
            out[fsz + (size_t)(NGRP * GB) * Hdim + (size_t)(grp * GB + m) * Hdim + u] = c_reg[r];
        }
    }
}

extern "C" void kernel_launch(void* const* d_in, const int* in_sizes, int n_in,
                              void* d_out, int out_size, void* d_ws, size_t ws_size,
                              hipStream_t stream) {
    const float* x    = (const float*)d_in[0];
    const float* h0   = (const float*)d_in[1];
    const float* c0   = (const float*)d_in[2];
    const float* wx   = (const float*)d_in[3];
    const float* wh   = (const float*)d_in[4];
    const float* bias = (const float*)d_in[5];
    float* out = (float*)d_out;
    uint32_t* flags = (uint32_t*)d_ws;
    uint16_t* hbuf  = (uint16_t*)((char*)d_ws + HBUF_OFF);

    hipMemsetAsync(flags, 0, FLAG_BYTES, stream);

    void* args[] = {(void*)&x, (void*)&h0, (void*)&c0, (void*)&wx, (void*)&wh,
                    (void*)&bias, (void*)&out, (void*)&flags, (void*)&hbuf};
    hipLaunchCooperativeKernel((const void*)lstm_main, dim3(NSLICE * NGRP),
                               dim3(NTHREADS), args, 0, stream);
}

// Round 6
// 2308.392 us; speedup vs baseline: 11.7093x; 1.1267x over previous
//
#include <hip/hip_runtime.h>
#include <hip/hip_fp16.h>
#include <stdint.h>

#define Tdim 1024
#define INdim 256
#define Hdim 256
#define COLS 1024
#define NSLICE 8
#define NGRP 8
#define GB 16          // batches per group (MFMA M)
#define UPB 32         // units per slice
#define CPB 128        // cols per block
#define NTHREADS 512
#define FLAG_STRIDE ((Tdim + 1) * NSLICE)
#define FLAG_BYTES (NGRP * FLAG_STRIDE * 4)   // 262,400
#define HBUF_OFF 266240                        // hbuf: [2][NGRP][GB][Hdim] f16 = 131,072 B

typedef _Float16 half8 __attribute__((ext_vector_type(8)));
typedef float f32x4 __attribute__((ext_vector_type(4)));

__device__ __forceinline__ uint16_t f2h(float f) {
    __half h = __float2half(f);
    return *reinterpret_cast<uint16_t*>(&h);
}
__device__ __forceinline__ uint32_t pk2(float lo, float hi) {
    return (uint32_t)f2h(lo) | ((uint32_t)f2h(hi) << 16);
}
__device__ __forceinline__ float sigm(float v) {
    return __builtin_amdgcn_rcpf(1.f + __expf(-v));
}
__device__ __forceinline__ float tanhfast(float v) {
    float e = __expf(2.f * v);
    return 1.f - 2.f * __builtin_amdgcn_rcpf(e + 1.f);
}
__device__ __forceinline__ size_t hb_idx(int par, int grp, int m, int u) {
    return ((((size_t)par * NGRP + grp) * GB + m) << 8) | (size_t)u;
}

// MFMA 16x16x32 f16 lane roles (verified passing r4/r5):
//   A: lane l -> row(m) = l&15, k = (l>>4)*8 + e
//   B: lane l -> col    = l&15 (per-lane W regs), k = (l>>4)*8 + e
//   C/D: lane l, reg r -> row(m) = (l>>4)*4 + r, col = l&15
__global__ __launch_bounds__(NTHREADS, 1) void lstm_main(
    const float* __restrict__ x, const float* __restrict__ h0,
    const float* __restrict__ c0, const float* __restrict__ wx,
    const float* __restrict__ wh, const float* __restrict__ bias,
    float* __restrict__ out, uint32_t* flags, uint16_t* hbuf)
{
    const int tid   = threadIdx.x;
    const int grp   = blockIdx.x & 7;     // slices of a grp share an XCD (perf heuristic only)
    const int slice = blockIdx.x >> 3;
    const int lane  = tid & 63;
    const int wave  = tid >> 6;
    const int cw    = lane & 15;
    const int lhi   = lane >> 4;          // 0..3
    const int cl    = wave * 16 + cw;     // block-local col: (u_local<<2)|g
    const int g     = cl & 3;
    const int ul    = cl >> 2;            // 0..31
    const int u     = slice * UPB + ul;
    const int gcol  = g * Hdim + u;

    __shared__ __align__(16) uint16_t Wl[CPB * 512];     // 128 KB (prologue only)
    __shared__ __align__(16) uint16_t X[2][GB][32][8];   // 16 KB, m-major, slot=ko^(m&7)
    __shared__ __align__(16) uint16_t Hs[GB][32][8];     // 8 KB, same swizzle
    __shared__ __align__(16) uint16_t Hp16[GB][UPB];     // 1 KB   publish staging (f16)
    __shared__ __align__(16) float    Hpf[GB][UPB];      // 2 KB   fullh staging (f32)

    // ---------- prologue ----------
    for (int idx = tid; idx < CPB * 512; idx += NTHREADS) {
        int k  = idx >> 7;
        int ci = idx & 127;
        int uu = ci & 31, gg = ci >> 5;
        int cg = gg * Hdim + slice * UPB + uu;          // global col (coalesced over uu)
        int c  = (uu << 2) | gg;                        // block-local col
        float w = (k < INdim) ? wx[(size_t)k * COLS + cg]
                              : wh[(size_t)(k - INdim) * COLS + cg];
        int e = c * 512 + ((((k >> 3) ^ (c & 7)) << 3) | (k & 7));
        Wl[e] = f2h(w);
    }
    const int m_s   = tid >> 5;           // staging row (batch)
    const int ko_s  = tid & 31;           // staging k-oct
    const int slt_s = ko_s ^ (m_s & 7);   // swizzled slot for staging writes
    {   // stage x_0 directly (conflict-free b128 write)
        const float4* xs = reinterpret_cast<const float4*>(
            &x[((size_t)(grp * GB + m_s) * Tdim + 0) * INdim + ko_s * 8]);
        float4 a = xs[0], b = xs[1];
        uint4 pkv = {pk2(a.x, a.y), pk2(a.z, a.w), pk2(b.x, b.y), pk2(b.z, b.w)};
        *reinterpret_cast<uint4*>(&X[0][m_s][slt_s][0]) = pkv;
    }
    // prefetch x_1 into regs
    float4 xp0, xp1;
    {
        const float4* xs = reinterpret_cast<const float4*>(
            &x[((size_t)(grp * GB + m_s) * Tdim + 1) * INdim + ko_s * 8]);
        xp0 = xs[0]; xp1 = xs[1];
    }
    if (tid < 64) {  // h0 -> hbuf[0] (own slice's units), relaxed 8B stores
        int m = tid >> 2, uo = tid & 3;
        int u0 = slice * UPB + uo * 8;
        const float4* hs = reinterpret_cast<const float4*>(
            &h0[(size_t)(grp * GB + m) * Hdim + u0]);
        float4 a = hs[0], b = hs[1];
        unsigned long long p0 =
            (unsigned long long)pk2(a.x, a.y) | ((unsigned long long)pk2(a.z, a.w) << 32);
        unsigned long long p1 =
            (unsigned long long)pk2(b.x, b.y) | ((unsigned long long)pk2(b.z, b.w) << 32);
        unsigned long long* hp =
            reinterpret_cast<unsigned long long*>(&hbuf[hb_idx(0, grp, m, u0)]);
        __hip_atomic_store(&hp[0], p0, __ATOMIC_RELAXED, __HIP_MEMORY_SCOPE_AGENT);
        __hip_atomic_store(&hp[1], p1, __ATOMIC_RELAXED, __HIP_MEMORY_SCOPE_AGENT);
    }
    float c_reg[4];
    #pragma unroll
    for (int r = 0; r < 4; ++r)
        c_reg[r] = c0[(size_t)(grp * GB + lhi * 4 + r) * Hdim + u];
    const float bv = bias[gcol];
    __syncthreads();   // Wl/X0 staged; hbuf init drained (implicit vmcnt(0))
    uint32_t* fl = flags + grp * FLAG_STRIDE;
    if (tid == 0)
        __hip_atomic_store(&fl[slice], 1u, __ATOMIC_RELAXED, __HIP_MEMORY_SCOPE_AGENT);

    // W fragments -> registers (one-time; Wl dead afterwards).
    // Wf[i] = B-frag for MFMA i: col=cw, k-oct = i*4 + lhi  (i 0..7 = x-part, 8..15 = h-part)
    const uint32_t swz = (uint32_t)(cl & 7);
    const uint16_t* wrow = &Wl[cl * 512];
    half8 Wf[16];
    #pragma unroll
    for (int i = 0; i < 16; ++i)
        Wf[i] = *reinterpret_cast<const half8*>(&wrow[(((uint32_t)(i * 4 + lhi)) ^ swz) << 3]);

    const int swz_a = cw & 7;             // A-read slot xor (row = cw)
    float hv[4] = {0.f, 0.f, 0.f, 0.f};

    // ---------- time loop ----------
    for (int t = 0; t < Tdim; ++t) {
        const int par = t & 1, pn = par ^ 1;

        // stage x_{t+1} from regs (loaded last iteration; single b128, conflict-free)
        {
            uint4 pkv = {pk2(xp0.x, xp0.y), pk2(xp0.z, xp0.w),
                         pk2(xp1.x, xp1.y), pk2(xp1.z, xp1.w)};
            *reinterpret_cast<uint4*>(&X[pn][m_s][slt_s][0]) = pkv;
        }
        // issue prefetch of x_{t+2}
        {
            int tn = (t + 2 < Tdim) ? t + 2 : Tdim - 1;
            const float4* xs = reinterpret_cast<const float4*>(
                &x[((size_t)(grp * GB + m_s) * Tdim + tn) * INdim + ko_s * 8]);
            xp0 = xs[0]; xp1 = xs[1];
        }

        // x-part GEMM (k 0..255) — independent of h(t)
        f32x4 acc0 = {0.f, 0.f, 0.f, 0.f}, acc1 = {0.f, 0.f, 0.f, 0.f};
        #pragma unroll
        for (int s = 0; s < 8; s += 2) {
            int ko0 = s * 4 + lhi, ko1 = ko0 + 4;
            half8 a0 = *reinterpret_cast<const half8*>(&X[par][cw][ko0 ^ swz_a][0]);
            acc0 = __builtin_amdgcn_mfma_f32_16x16x32_f16(a0, Wf[s], acc0, 0, 0, 0);
            half8 a1 = *reinterpret_cast<const half8*>(&X[par][cw][ko1 ^ swz_a][0]);
            acc1 = __builtin_amdgcn_mfma_f32_16x16x32_f16(a1, Wf[s + 1], acc1, 0, 0, 0);
        }

        // wait for h(t) from all 8 slices — relaxed polls, no cache maintenance
        if (tid < NSLICE) {
            while (__hip_atomic_load(&fl[t * NSLICE + tid], __ATOMIC_RELAXED,
                                     __HIP_MEMORY_SCOPE_AGENT) == 0) {}
        }
        __syncthreads();

        // stage h -> Hs (relaxed coherence-point loads, one b128 LDS write)
        {
            const unsigned long long* hp = reinterpret_cast<const unsigned long long*>(
                &hbuf[hb_idx(par, grp, m_s, ko_s * 8)]);
            unsigned long long h0v = __hip_atomic_load(&hp[0], __ATOMIC_RELAXED,
                                                       __HIP_MEMORY_SCOPE_AGENT);
            unsigned long long h1v = __hip_atomic_load(&hp[1], __ATOMIC_RELAXED,
                                                       __HIP_MEMORY_SCOPE_AGENT);
            uint4 hw = {(uint32_t)h0v, (uint32_t)(h0v >> 32),
                        (uint32_t)h1v, (uint32_t)(h1v >> 32)};
            *reinterpret_cast<uint4*>(&Hs[m_s][slt_s][0]) = hw;
        }
        __syncthreads();

        // h-part GEMM (k 256..511)
        #pragma unroll
        for (int s = 0; s < 8; s += 2) {
            int ko0 = s * 4 + lhi, ko1 = ko0 + 4;
            half8 a0 = *reinterpret_cast<const half8*>(&Hs[cw][ko0 ^ swz_a][0]);
            acc0 = __builtin_amdgcn_mfma_f32_16x16x32_f16(a0, Wf[8 + s], acc0, 0, 0, 0);
            half8 a1 = *reinterpret_cast<const half8*>(&Hs[cw][ko1 ^ swz_a][0]);
            acc1 = __builtin_amdgcn_mfma_f32_16x16x32_f16(a1, Wf[9 + s], acc1, 0, 0, 0);
        }

        // gates + state update (4 rows per lane)
        #pragma unroll
        for (int r = 0; r < 4; ++r) {
            float tval = acc0[r] + acc1[r] + bv;
            float act = (g == 3) ? tanhfast(tval) : sigm(tval);
            float x1  = __shfl_xor(act, 1);
            float e0  = (g & 1) ? x1 : act;
            float o1  = (g & 1) ? act : x1;
            float e0s = __shfl_xor(e0, 2);
            float o1s = __shfl_xor(o1, 2);
            float f_ = (g < 2) ? e0  : e0s;
            float i_ = (g < 2) ? o1  : o1s;
            float o_ = (g < 2) ? e0s : e0;
            float g_ = (g < 2) ? o1s : o1;
            c_reg[r] = fmaf(c_reg[r], f_, g_ * i_);
            hv[r] = tanhfast(c_reg[r]) * o_;
        }

        // drop h into LDS staging tiles
        if (g == 0) {
            #pragma unroll
            for (int r = 0; r < 4; ++r) {
                int m = lhi * 4 + r;
                Hp16[m][ul] = f2h(hv[r]);
                Hpf[m][ul]  = hv[r];
            }
        }
        __syncthreads();

        // publish: 128 coalesced 8B relaxed stores (16 full cache lines)
        if (tid < 128) {
            int m = tid >> 3, q = tid & 7;
            unsigned long long v =
                *reinterpret_cast<const unsigned long long*>(&Hp16[m][q * 4]);
            __hip_atomic_store(reinterpret_cast<unsigned long long*>(
                                   &hbuf[hb_idx(pn, grp, m, slice * UPB + q * 4)]),
                               v, __ATOMIC_RELAXED, __HIP_MEMORY_SCOPE_AGENT);
        }
        __syncthreads();   // implicit vmcnt(0): publish acked before flag
        if (tid == 0)
            __hip_atomic_store(&fl[(t + 1) * NSLICE + slice], 1u,
                               __ATOMIC_RELAXED, __HIP_MEMORY_SCOPE_AGENT);

        // fullh stores — after the flag, off the critical path (waves 2-3)
        if (tid >= 128 && tid < 256) {
            int j = tid - 128;
            int m = j >> 3, q = j & 7;
            float4 v = *reinterpret_cast<const float4*>(&Hpf[m][q * 4]);
            *reinterpret_cast<float4*>(
                &out[((size_t)(grp * GB + m) * Tdim + t) * Hdim + slice * UPB + q * 4]) = v;
        }
    }

    // final h_f, c_f
    if (g == 0) {
        const size_t fsz = (size_t)(NGRP * GB) * Tdim * Hdim;
        #pragma unroll
        for (int r = 0; r < 4; ++r) {
            int m = lhi * 4 + r;
            out[fsz + (size_t)(grp * GB + m) * Hdim + u] = hv[r];
            out[fsz + (size_t)(NGRP * GB) * Hdim + (size_t)(grp * GB + m) * Hdim + u] = c_reg[r];
        }
    }
}

extern "C" void kernel_launch(void* const* d_in, const int* in_sizes, int n_in,
                              void* d_out, int out_size, void* d_ws, size_t ws_size,
                              hipStream_t stream) {
    const float* x    = (const float*)d_in[0];
    const float* h0   = (const float*)d_in[1];
    const float* c0   = (const float*)d_in[2];
    const float* wx   = (const float*)d_in[3];
    const float* wh   = (const float*)d_in[4];
    const float* bias = (const float*)d_in[5];
    float* out = (float*)d_out;
    uint32_t* flags = (uint32_t*)d_ws;
    uint16_t* hbuf  = (uint16_t*)((char*)d_ws + HBUF_OFF);

    hipMemsetAsync(flags, 0, FLAG_BYTES, stream);

    void* args[] = {(void*)&x, (void*)&h0, (void*)&c0, (void*)&wx, (void*)&wh,
                    (void*)&bias, (void*)&out, (void*)&flags, (void*)&hbuf};
    hipLaunchCooperativeKernel((const void*)lstm_main, dim3(NSLICE * NGRP),
                               dim3(NTHREADS), args, 0, stream);
}